// Round 2
// baseline (3202.572 us; speedup 1.0000x reference)
//
#include <hip/hip_runtime.h>
#include <math.h>

typedef __attribute__((ext_vector_type(4))) float f32x4v;
typedef __attribute__((ext_vector_type(8))) __bf16 bf16x8v;

#define SCALE 0.17677669529663687f
#define TOK 131072
#define MCHUNK 32768

__device__ __forceinline__ ushort f2bf(float v){
  uint x = __float_as_uint(v);
  return (ushort)((x + 0x7fffu + ((x >> 16) & 1u)) >> 16);
}
__device__ __forceinline__ uint pack2(float lo, float hi){
  return (uint)f2bf(lo) | ((uint)f2bf(hi) << 16);
}
__device__ __forceinline__ float bflo(uint u){ return __uint_as_float(u << 16); }
__device__ __forceinline__ float bfhi(uint u){ return __uint_as_float(u & 0xffff0000u); }

// ---------------- weight f32 -> bf16 convert ----------------
__global__ __launch_bounds__(256) void cvtw_k(const float* __restrict__ src,
    ushort* __restrict__ dst, int n4){
  const int i = blockIdx.x * 256 + threadIdx.x;
  if (i >= n4) return;
  float4 v = ((const float4*)src)[i];
  ushort4 o = { f2bf(v.x), f2bf(v.y), f2bf(v.z), f2bf(v.w) };
  ((ushort4*)dst)[i] = o;
}

// ---------------- row stats over X1 chunk [rows][2048] bf16 ----------------
__global__ __launch_bounds__(256) void rowstats_k(const ushort* __restrict__ X,
    float* __restrict__ stats){
  const int row = blockIdx.x, tid = threadIdx.x;
  uint4 u = *(const uint4*)(X + (long)row * 2048 + tid * 8);
  float s = 0.f, q = 0.f;
  uint* e = (uint*)&u;
  #pragma unroll
  for (int c = 0; c < 4; ++c){
    float a = bflo(e[c]), b2 = bfhi(e[c]);
    s += a + b2; q += a * a + b2 * b2;
  }
  #pragma unroll
  for (int o = 1; o < 64; o <<= 1){ s += __shfl_xor(s, o); q += __shfl_xor(q, o); }
  __shared__ float ss[4], qs[4];
  if ((tid & 63) == 0){ ss[tid >> 6] = s; qs[tid >> 6] = q; }
  __syncthreads();
  if (tid == 0){
    float S = ss[0] + ss[1] + ss[2] + ss[3];
    float Q = qs[0] + qs[1] + qs[2] + qs[3];
    float mean = S * (1.f / 2048.f);
    float var = Q * (1.f / 2048.f) - mean * mean;
    stats[row * 2] = mean;
    stats[row * 2 + 1] = rsqrtf(var + 1e-5f);
  }
}

// ---------------- row stats over x f32 [T][256] ----------------
__global__ __launch_bounds__(256) void stats256_k(const float* __restrict__ x,
    float* __restrict__ stats){
  const int lane = threadIdx.x & 63, wid = threadIdx.x >> 6;
  const long row = (long)blockIdx.x * 4 + wid;
  float4 v = *(const float4*)(x + row * 256 + lane * 4);
  float s = v.x + v.y + v.z + v.w;
  float q = v.x * v.x + v.y * v.y + v.z * v.z + v.w * v.w;
  #pragma unroll
  for (int o = 1; o < 64; o <<= 1){ s += __shfl_xor(s, o); q += __shfl_xor(q, o); }
  if (lane == 0){
    float mean = s * (1.f / 256.f);
    float var = q * (1.f / 256.f) - mean * mean;
    stats[row * 2] = mean;
    stats[row * 2 + 1] = rsqrtf(var + 1e-5f);
  }
}

// ---------------- bf16 MFMA GEMM: C[M,N] = epilogue(A[M,K] @ W[N,K]^T + bias) ----------------
// ACT: 0 none, 1 leaky(0.01), 2 gelu(exact). OUTT: 0 f32, 1 bf16.
// RES: 0 none, 1 +res, 2 +res+pcd.
// AMODE: 0 bf16 A; 1 bf16 A + LN(stats,lng,lnb); 2 f32 A + LN(stats,lng,lnb);
//        3 concat f32 (lng=pcd rows, lnb=img rows), K=512.
template<int ACT, int OUTT, int RES, int AMODE>
__global__ __launch_bounds__(256) void gemm_k(
    const void* __restrict__ Av, const ushort* __restrict__ W,
    const float* __restrict__ bias, void* __restrict__ outp,
    const float* __restrict__ res, const float* __restrict__ pcdp,
    const float* __restrict__ stats, const float* __restrict__ lng,
    const float* __restrict__ lnb, int M, int N, int K)
{
  __shared__ ushort As[128][40];
  __shared__ ushort Bs[128][40];
  const int tid = threadIdx.x;
  const int lane = tid & 63, wid = tid >> 6;
  const int wr = wid >> 1, wc = wid & 1;
  const int mBase = blockIdx.y * 128, nBase = blockIdx.x * 128;
  const int fr = lane & 15, grp = lane >> 4;
  f32x4v acc[4][4];
  #pragma unroll
  for (int i = 0; i < 4; ++i)
    #pragma unroll
    for (int j = 0; j < 4; ++j) acc[i][j] = (f32x4v){0.f, 0.f, 0.f, 0.f};
  const int srow = tid >> 1, skh = (tid & 1) * 16;
  const int arow = mBase + srow;
  const ushort* Wp = W + (long)(nBase + srow) * K + skh;
  float meanv = 0.f, rstdv = 0.f;
  if (AMODE == 1 || AMODE == 2){
    meanv = stats[arow * 2]; rstdv = stats[arow * 2 + 1];
  }
  for (int kt = 0; kt < K; kt += 32){
    __syncthreads();
    uint4 a0, a1;
    if (AMODE == 0 || AMODE == 1){
      const ushort* Ap = (const ushort*)Av + (long)arow * K + skh + kt;
      a0 = *(const uint4*)Ap;
      a1 = *(const uint4*)(Ap + 8);
      if (AMODE == 1){
        const float* gp = lng + kt + skh;
        const float* bp = lnb + kt + skh;
        uint* e = (uint*)&a0;
        #pragma unroll
        for (int c = 0; c < 4; ++c){
          float lo = (bflo(e[c]) - meanv) * rstdv * gp[c * 2]     + bp[c * 2];
          float hi = (bfhi(e[c]) - meanv) * rstdv * gp[c * 2 + 1] + bp[c * 2 + 1];
          e[c] = pack2(lo, hi);
        }
        uint* e1 = (uint*)&a1;
        #pragma unroll
        for (int c = 0; c < 4; ++c){
          float lo = (bflo(e1[c]) - meanv) * rstdv * gp[8 + c * 2]     + bp[8 + c * 2];
          float hi = (bfhi(e1[c]) - meanv) * rstdv * gp[8 + c * 2 + 1] + bp[8 + c * 2 + 1];
          e1[c] = pack2(lo, hi);
        }
      }
    } else if (AMODE == 2){
      const float* Ap = (const float*)Av + (long)arow * K + kt + skh;
      float4 f0 = *(const float4*)(Ap + 0);
      float4 f1 = *(const float4*)(Ap + 4);
      float4 f2 = *(const float4*)(Ap + 8);
      float4 f3 = *(const float4*)(Ap + 12);
      const float* gp = lng + kt + skh;
      const float* bp = lnb + kt + skh;
      float f[16] = { f0.x,f0.y,f0.z,f0.w, f1.x,f1.y,f1.z,f1.w,
                      f2.x,f2.y,f2.z,f2.w, f3.x,f3.y,f3.z,f3.w };
      uint e[8];
      #pragma unroll
      for (int c = 0; c < 8; ++c){
        float lo = (f[c * 2]     - meanv) * rstdv * gp[c * 2]     + bp[c * 2];
        float hi = (f[c * 2 + 1] - meanv) * rstdv * gp[c * 2 + 1] + bp[c * 2 + 1];
        e[c] = pack2(lo, hi);
      }
      a0 = *(uint4*)&e[0];
      a1 = *(uint4*)&e[4];
    } else { // AMODE == 3 : concat pcd|img f32, K = 512
      const int col = kt + skh;
      const float* src = (col < 256) ? (lng + (long)arow * 256 + col)
                                     : (lnb + (long)arow * 256 + (col - 256));
      float4 f0 = *(const float4*)(src + 0);
      float4 f1 = *(const float4*)(src + 4);
      float4 f2 = *(const float4*)(src + 8);
      float4 f3 = *(const float4*)(src + 12);
      uint e[8];
      e[0] = pack2(f0.x, f0.y); e[1] = pack2(f0.z, f0.w);
      e[2] = pack2(f1.x, f1.y); e[3] = pack2(f1.z, f1.w);
      e[4] = pack2(f2.x, f2.y); e[5] = pack2(f2.z, f2.w);
      e[6] = pack2(f3.x, f3.y); e[7] = pack2(f3.z, f3.w);
      a0 = *(uint4*)&e[0];
      a1 = *(uint4*)&e[4];
    }
    *(uint4*)&As[srow][skh]     = a0;
    *(uint4*)&As[srow][skh + 8] = a1;
    uint4 b0 = *(const uint4*)(Wp + kt);
    uint4 b1 = *(const uint4*)(Wp + kt + 8);
    *(uint4*)&Bs[srow][skh]     = b0;
    *(uint4*)&Bs[srow][skh + 8] = b1;
    __syncthreads();
    bf16x8v af[4], bfv[4];
    #pragma unroll
    for (int i = 0; i < 4; ++i) af[i]  = *(const bf16x8v*)&As[wr * 64 + i * 16 + fr][grp * 8];
    #pragma unroll
    for (int j = 0; j < 4; ++j) bfv[j] = *(const bf16x8v*)&Bs[wc * 64 + j * 16 + fr][grp * 8];
    #pragma unroll
    for (int i = 0; i < 4; ++i)
      #pragma unroll
      for (int j = 0; j < 4; ++j)
        acc[i][j] = __builtin_amdgcn_mfma_f32_16x16x32_bf16(af[i], bfv[j], acc[i][j], 0, 0, 0);
  }
  #pragma unroll
  for (int j = 0; j < 4; ++j){
    const int n = nBase + wc * 64 + j * 16 + fr;
    const float bn = bias[n];
    #pragma unroll
    for (int i = 0; i < 4; ++i){
      #pragma unroll
      for (int rr = 0; rr < 4; ++rr){
        const long m = mBase + wr * 64 + i * 16 + grp * 4 + rr;
        float v = acc[i][j][rr] + bn;
        if (ACT == 1) v = v > 0.f ? v : 0.01f * v;
        if (ACT == 2) v = 0.5f * v * (1.f + erff(v * 0.70710678118f));
        if (RES >= 1) v += res[m * N + n];
        if (RES == 2) v += pcdp[m * N + n];
        if (OUTT == 0) ((float*)outp)[m * N + n] = v;
        else           ((ushort*)outp)[m * N + n] = f2bf(v);
      }
    }
  }
}

// ---------------- window attention: one wave per (window, head) ----------------
template<int SHIFT>
__global__ __launch_bounds__(64) void attn_k(const ushort* __restrict__ qkv,
    const float* __restrict__ rpb, ushort* __restrict__ outp)
{
  __shared__ float Kf[64][36];
  __shared__ float Vf[64][36];
  __shared__ float bias_s[225];
  __shared__ int code_s[64];
  const int l = threadIdx.x;
  const int head = blockIdx.x & 7;
  const int bw = blockIdx.x >> 3;
  const int b = bw >> 10, widx = bw & 1023;
  const int wh = widx >> 5, ww = widx & 31;
  for (int i = l; i < 225; i += 64) bias_s[i] = rpb[i * 8 + head];
  const int th = l >> 3, tw = l & 7;
  const int h = wh * 8 + th, w = ww * 8 + tw;
  int mycode = 0;
  if (SHIFT > 0){
    const int rh = (h < 248) ? 0 : ((h < 256 - SHIFT) ? 1 : 2);
    const int rw = (w < 248) ? 0 : ((w < 256 - SHIFT) ? 1 : 2);
    mycode = rh * 3 + rw;
    code_s[l] = mycode;
  }
  const int hs = (h + SHIFT) & 255;
  const int wsm = (w + SHIFT) & 255;
  const long tok = ((long)b * 256 + hs) * 256 + wsm;
  const ushort* qb = qkv + tok * 768 + head * 32;
  float q[32];
  #pragma unroll
  for (int d2 = 0; d2 < 16; ++d2){
    const uint u = *(const uint*)(qb + d2 * 2);
    q[d2 * 2]     = bflo(u) * SCALE;
    q[d2 * 2 + 1] = bfhi(u) * SCALE;
  }
  #pragma unroll
  for (int d2 = 0; d2 < 16; ++d2){
    const uint uk = *(const uint*)(qb + 256 + d2 * 2);
    Kf[l][d2 * 2]     = bflo(uk);
    Kf[l][d2 * 2 + 1] = bfhi(uk);
    const uint uv = *(const uint*)(qb + 512 + d2 * 2);
    Vf[l][d2 * 2]     = bflo(uv);
    Vf[l][d2 * 2 + 1] = bfhi(uv);
  }
  __syncthreads();
  f32x4v o[8];
  #pragma unroll
  for (int d4 = 0; d4 < 8; ++d4) o[d4] = (f32x4v){0.f, 0.f, 0.f, 0.f};
  float sum = 0.f;
  for (int k = 0; k < 64; ++k){
    float s0 = 0.f, s1 = 0.f, s2 = 0.f, s3 = 0.f;
    #pragma unroll
    for (int d4 = 0; d4 < 8; ++d4){
      const f32x4v kv = *(const f32x4v*)&Kf[k][d4 * 4];
      s0 += q[d4 * 4 + 0] * kv[0];
      s1 += q[d4 * 4 + 1] * kv[1];
      s2 += q[d4 * 4 + 2] * kv[2];
      s3 += q[d4 * 4 + 3] * kv[3];
    }
    float s = (s0 + s1) + (s2 + s3);
    s += bias_s[(th - (k >> 3) + 7) * 15 + (tw - (k & 7) + 7)];
    if (SHIFT > 0 && mycode != code_s[k]) s -= 100.f;
    const float p = __expf(s);
    sum += p;
    #pragma unroll
    for (int d4 = 0; d4 < 8; ++d4){
      const f32x4v vv = *(const f32x4v*)&Vf[k][d4 * 4];
      o[d4] += p * vv;
    }
  }
  const float inv = 1.f / sum;
  ushort* ob = outp + tok * 256 + head * 32;
  #pragma unroll
  for (int d4 = 0; d4 < 8; ++d4){
    ushort4 ov = { f2bf(o[d4][0] * inv), f2bf(o[d4][1] * inv),
                   f2bf(o[d4][2] * inv), f2bf(o[d4][3] * inv) };
    *(ushort4*)(ob + d4 * 4) = ov;
  }
}

extern "C" void kernel_launch(void* const* d_in, const int* in_sizes, int n_in,
                              void* d_out, int out_size, void* d_ws, size_t ws_size,
                              hipStream_t stream){
  const float* pcd    = (const float*)d_in[0];
  const float* img    = (const float*)d_in[1];
  const float* rd_w1  = (const float*)d_in[2];
  const float* rd_b1  = (const float*)d_in[3];
  const float* rd_lng = (const float*)d_in[4];
  const float* rd_lnb = (const float*)d_in[5];
  const float* rd_w2  = (const float*)d_in[6];
  const float* rd_b2  = (const float*)d_in[7];
  const float* n1g    = (const float*)d_in[8];
  const float* n1b    = (const float*)d_in[9];
  const float* qkv_w  = (const float*)d_in[10];
  const float* qkv_b  = (const float*)d_in[11];
  const float* rpb    = (const float*)d_in[12];
  const float* proj_w = (const float*)d_in[13];
  const float* proj_b = (const float*)d_in[14];
  const float* n2g    = (const float*)d_in[15];
  const float* n2b    = (const float*)d_in[16];
  const float* mlp_w1 = (const float*)d_in[17];
  const float* mlp_b1 = (const float*)d_in[18];
  const float* mlp_w2 = (const float*)d_in[19];
  const float* mlp_b2 = (const float*)d_in[20];

  char* ws = (char*)d_ws;
  ushort* w1b    = (ushort*)(ws + 0);                // 2048x512 bf16  (2 MB)
  ushort* w2b    = (ushort*)(ws + 2097152);          // 256x2048       (1 MB)
  ushort* qkvwb  = (ushort*)(ws + 3145728);          // 2x768x256      (0.75 MB)
  ushort* projwb = (ushort*)(ws + 3932160);          // 2x256x256      (0.25 MB)
  ushort* mlp1wb = (ushort*)(ws + 4194304);          // 2x1024x256     (1 MB)
  ushort* mlp2wb = (ushort*)(ws + 5242880);          // 2x256x1024     (1 MB)
  float*  stats  = (float*)(ws + 6291456);           // T x 2 f32      (1 MB)
  char*   big    = ws + 7340032;                     // 335,544,320 B region
  ushort* X1c    = (ushort*)big;                     // 32768 x 2048 bf16 (134 MB)
  ushort* qkvb   = (ushort*)big;                     // T x 768 bf16      (201 MB)
  ushort* attno  = (ushort*)(big + 201326592);       // T x 256 bf16      (67 MB)
  ushort* hidden = (ushort*)(big + 268435456);       // 32768 x 1024 bf16 (67 MB)
  float* x = (float*)d_out;                          // residual stream, f32
  // peak ws use = 7340032 + 335544320 = 342,884,352 bytes

  cvtw_k<<<1024, 256, 0, stream>>>(rd_w1, w1b, 262144);
  cvtw_k<<<512,  256, 0, stream>>>(rd_w2, w2b, 131072);
  cvtw_k<<<384,  256, 0, stream>>>(qkv_w, qkvwb, 98304);
  cvtw_k<<<128,  256, 0, stream>>>(proj_w, projwb, 32768);
  cvtw_k<<<512,  256, 0, stream>>>(mlp_w1, mlp1wb, 131072);
  cvtw_k<<<512,  256, 0, stream>>>(mlp_w2, mlp2wb, 131072);

  // ---- reduce block, chunked over M ----
  for (int c = 0; c < 4; ++c){
    const long off = (long)c * MCHUNK;
    gemm_k<1,1,0,3><<<dim3(16,256), 256, 0, stream>>>(nullptr, w1b, rd_b1, X1c,
        nullptr, nullptr, nullptr, pcd + off*256, img + off*256, MCHUNK, 2048, 512);
    rowstats_k<<<MCHUNK, 256, 0, stream>>>(X1c, stats + off*2);
    gemm_k<0,0,0,1><<<dim3(2,256), 256, 0, stream>>>(X1c, w2b, rd_b2, x + off*256,
        nullptr, nullptr, stats + off*2, rd_lng, rd_lnb, MCHUNK, 256, 2048);
  }

  // ---- Swin layers ----
  for (int i = 0; i < 2; ++i){
    stats256_k<<<TOK/4, 256, 0, stream>>>(x, stats);
    gemm_k<0,1,0,2><<<dim3(6,1024), 256, 0, stream>>>(x, qkvwb + i*196608,
        qkv_b + i*768, qkvb, nullptr, nullptr, stats, n1g + i*256, n1b + i*256,
        TOK, 768, 256);
    if (i == 0)
      attn_k<0><<<16384, 64, 0, stream>>>(qkvb, rpb, attno);
    else
      attn_k<4><<<16384, 64, 0, stream>>>(qkvb, rpb + 1800, attno);
    gemm_k<0,0,1,0><<<dim3(2,1024), 256, 0, stream>>>(attno, projwb + i*65536,
        proj_b + i*256, x, x, nullptr, nullptr, nullptr, nullptr, TOK, 256, 256);
    stats256_k<<<TOK/4, 256, 0, stream>>>(x, stats);
    for (int c = 0; c < 4; ++c){
      const long off = (long)c * MCHUNK;
      gemm_k<2,1,0,2><<<dim3(8,256), 256, 0, stream>>>(x + off*256, mlp1wb + i*262144,
          mlp_b1 + i*1024, hidden, nullptr, nullptr, stats + off*2,
          n2g + i*256, n2b + i*256, MCHUNK, 1024, 256);
      if (i == 0)
        gemm_k<0,0,1,0><<<dim3(2,256), 256, 0, stream>>>(hidden, mlp2wb + i*262144,
            mlp_b2 + i*256, x + off*256, x + off*256, nullptr, nullptr, nullptr, nullptr,
            MCHUNK, 256, 1024);
      else
        gemm_k<0,0,2,0><<<dim3(2,256), 256, 0, stream>>>(hidden, mlp2wb + i*262144,
            mlp_b2 + i*256, x + off*256, x + off*256, pcd + off*256, nullptr, nullptr, nullptr,
            MCHUNK, 256, 1024);
    }
  }
}